// Round 8
// baseline (598.407 us; speedup 1.0000x reference)
//
#include <hip/hip_runtime.h>
#include <hip/hip_cooperative_groups.h>
#include <stdint.h>

namespace cg = cooperative_groups;
typedef unsigned long long u64;

// key: ((b*41+z)<<20) | y<<10 | x   (b<4, z<41, y,x<1024)
// -> 164*2^20 = 171,966,464 keys; monotone-equivalent to reference hash
// b*1025^3+z*1025^2+y*1025+x (lex order (b,z,y,x) preserved, bijective).
#define NWORDS 2686976u             // 164*2^20/64 words
#define GW 4096u                    // words per block (256 thr x 16 words)
#define NGROUPS 656u                // NWORDS/GW (exact)

// interleaved per-word record: presence bits + exclusive rank prefix.
// 16B so one probe = one global_load_dwordx4 = one cache line.
struct __align__(16) Combo { u64 word; uint32_t prefix; uint32_t pad; };
typedef u64 u64x2 __attribute__((ext_vector_type(2)));

__device__ __forceinline__ uint32_t pack4(int4 v) {
    // v = (b, z, y, x)
    return (((uint32_t)v.x * 41u + (uint32_t)v.y) << 20) |
           ((uint32_t)v.z << 10) | (uint32_t)v.w;
}

// ---------------- fused setup (cooperative): zero -> set bits -> rank -> emit ----------------
__global__ void build_all(const int* __restrict__ sidx, Combo* __restrict__ combo,
                          uint32_t* __restrict__ cnt, uint32_t* __restrict__ groupSum,
                          float* __restrict__ outI, int ns) {
    cg::grid_group grid = cg::this_grid();
    __shared__ uint32_t s[256];
    const int tid = threadIdx.x, bid = blockIdx.x;
    const size_t w0 = (size_t)bid * GW + (size_t)tid * 16;
    const int gstride = (int)(gridDim.x * blockDim.x);
    const int gtid = bid * 256 + tid;

    // phase 0: zero combo (each block zeroes exactly the words it later ranks) + cnt
    u64x2 z2 = {0ull, 0ull};
    #pragma unroll
    for (int j = 0; j < 16; ++j) ((u64x2*)combo)[w0 + j] = z2;
    for (int i = gtid; i < ns; i += gstride) cnt[i] = 0u;
    grid.sync();

    // phase 1: presence bits (fire-and-forget atomicOr; round-6 lesson: no contended counters)
    for (int i = gtid; i < ns; i += gstride) {
        uint32_t k = pack4(((const int4*)sidx)[i]);
        atomicOr(&combo[k >> 6].word, 1ull << (k & 63u));
    }
    __threadfence();
    grid.sync();

    // phase 2: read own 16 words ONCE into registers; block-scan popcounts; publish block total
    u64 w[16];
    uint32_t tsum = 0;
    #pragma unroll
    for (int j = 0; j < 16; ++j) { w[j] = combo[w0 + j].word; tsum += (uint32_t)__popcll(w[j]); }
    s[tid] = tsum;
    __syncthreads();
    #pragma unroll
    for (int off = 1; off < 256; off <<= 1) {
        uint32_t u = (tid >= off) ? s[tid - off] : 0u;
        __syncthreads();
        s[tid] += u;
        __syncthreads();
    }
    uint32_t exclInBlock = s[tid] - tsum;
    if (tid == 255) groupSum[bid] = s[255];
    __threadfence();
    grid.sync();

    // phase 3: base = sum of preceding block totals (656 u32 -> trivial)
    uint32_t part = 0;
    for (int g = tid; g < bid; g += 256) part += groupSum[g];
    __syncthreads();
    s[tid] = part;
    __syncthreads();
    #pragma unroll
    for (int off = 128; off > 0; off >>= 1) {
        if (tid < off) s[tid] += s[tid + off];
        __syncthreads();
    }
    uint32_t run = s[0] + exclInBlock;

    // phase 4: write per-word prefix; enumerate set bits in order -> sorted decoded indice
    #pragma unroll
    for (int j = 0; j < 16; ++j) {
        combo[w0 + j].prefix = run;
        u64 word = w[j];
        uint32_t kw = (uint32_t)(w0 + j) << 6;
        while (word) {
            int b = (int)__builtin_ctzll(word);
            word &= word - 1;
            uint32_t k = kw | (uint32_t)b;
            uint32_t bz = k >> 20;
            ((float4*)outI)[run++] = make_float4(
                (float)(bz / 41u), (float)(bz % 41u),
                (float)((k >> 10) & 1023u), (float)(k & 1023u));
        }
    }
}

// ---------------- teacher probe: ONE 16B random load per row ----------------
__global__ void teacher_probe(const int* __restrict__ tidx, const Combo* __restrict__ combo,
                              uint32_t* __restrict__ cnt, int* __restrict__ pos, int nt) {
    int t = blockIdx.x * blockDim.x + threadIdx.x;
    if (t >= nt) return;
    uint32_t k = pack4(((const int4*)tidx)[t]);
    u64x2 e = ((const u64x2*)combo)[k >> 6];
    u64 word = e.x;
    u64 bit  = 1ull << (k & 63u);
    if (word & bit) {
        int p = (int)((uint32_t)e.y + (uint32_t)__popcll(word & (bit - 1ull)));
        pos[t] = p;
        atomicAdd(&cnt[p], 1u);
    } else {
        pos[t] = -1;
    }
}

// zero only multi-contributor rows; cnt==1 rows are fully overwritten by plain stores
__global__ void zero_multi(const uint32_t* __restrict__ cnt, float* __restrict__ feat, int ns) {
    int s = blockIdx.x * blockDim.x + threadIdx.x;
    if (s >= ns) return;
    if (cnt[s] > 1u) {
        float4* d4 = (float4*)(feat + (size_t)s * 32);
        #pragma unroll
        for (int q = 0; q < 8; ++q) d4[q] = make_float4(0.f, 0.f, 0.f, 0.f);
    }
}

// feature write: no search; pos precomputed. unique -> plain 128B store; multi -> atomicAdd
__global__ void teacher_write(const float* __restrict__ tfeat, const int* __restrict__ pos,
                              const uint32_t* __restrict__ cnt, float* __restrict__ feat, int nt) {
    int t = blockIdx.x * blockDim.x + threadIdx.x;
    if (t >= nt) return;
    int p = pos[t];
    if (p < 0) return;
    const float4* src = (const float4*)(tfeat + (size_t)t * 32);
    float* dst = feat + (size_t)p * 32;
    if (cnt[p] == 1u) {
        float4* d4 = (float4*)dst;
        #pragma unroll
        for (int q = 0; q < 8; ++q) d4[q] = src[q];
    } else {
        #pragma unroll
        for (int q = 0; q < 8; ++q) {
            float4 f = src[q];
            atomicAdd(dst + q * 4 + 0, f.x);
            atomicAdd(dst + q * 4 + 1, f.y);
            atomicAdd(dst + q * 4 + 2, f.z);
            atomicAdd(dst + q * 4 + 3, f.w);
        }
    }
}

extern "C" void kernel_launch(void* const* d_in, const int* in_sizes, int n_in,
                              void* d_out, int out_size, void* d_ws, size_t ws_size,
                              hipStream_t stream) {
    const float* tfeat = (const float*)d_in[0];
    const int*   tidx  = (const int*)d_in[1];
    const int*   sidx  = (const int*)d_in[2];

    int NT = in_sizes[1] / 4;
    int NS = in_sizes[2] / 4;

    float* feat = (float*)d_out;                        // [NS, 32]
    float* outI = (float*)d_out + (size_t)NS * 32;      // [NS, 4] as floats

    // workspace: [combo 43MiB][cnt NS*4][groupSum 656*4][pos NT*4]  (~54MB << 1GB)
    char* base = (char*)d_ws;
    Combo*    combo    = (Combo*)base;
    uint32_t* cnt      = (uint32_t*)(base + (size_t)NWORDS * sizeof(Combo));
    uint32_t* groupSum = cnt + NS;
    int*      pos      = (int*)(groupSum + NGROUPS);

    void* args[] = { (void*)&sidx, (void*)&combo, (void*)&cnt,
                     (void*)&groupSum, (void*)&outI, (void*)&NS };
    hipLaunchCooperativeKernel((void*)build_all, dim3(NGROUPS), dim3(256), args, 0, stream);

    teacher_probe<<<(NT + 255) / 256, 256, 0, stream>>>(tidx, combo, cnt, pos, NT);
    zero_multi<<<(NS + 255) / 256, 256, 0, stream>>>(cnt, feat, NS);
    teacher_write<<<(NT + 255) / 256, 256, 0, stream>>>(tfeat, pos, cnt, feat, NT);
}

// Round 9
// 228.792 us; speedup vs baseline: 2.6155x; 2.6155x over previous
//
#include <hip/hip_runtime.h>
#include <stdint.h>

typedef unsigned long long u64;
typedef u64 u64x2 __attribute__((ext_vector_type(2)));

// key: ((b*41+z)<<20) | y<<10 | x   (b<4, z<41, y,x<1024)
// -> 164*2^20 = 171,966,464 keys; monotone-equivalent to reference hash
// b*1025^3+z*1025^2+y*1025+x (lex order (b,z,y,x) preserved, bijective).
#define NWORDS 2686976u             // 164*2^20/64 words
#define GW 4096u                    // words per block (256 thr x 16 words)
#define NGROUPS 656u                // NWORDS/GW (exact)

// interleaved per-word record: presence bits + exclusive rank prefix.
// One teacher probe = ONE random 16B load (global_load_dwordx4) = one cache line.
struct __align__(16) Combo { u64 word; uint32_t prefix; uint32_t pad; };

__device__ __forceinline__ uint32_t pack4(int4 v) {
    // v = (b, z, y, x)
    return (((uint32_t)v.x * 41u + (uint32_t)v.y) << 20) |
           ((uint32_t)v.z << 10) | (uint32_t)v.w;
}

// ---------------- phase 1: presence bits ----------------
// Fire-and-forget atomicOr only (round-6 lesson: no contended counters, no return use).
__global__ void set_bits(const int* __restrict__ sidx, Combo* __restrict__ combo, int ns) {
    int i = blockIdx.x * blockDim.x + threadIdx.x;
    if (i >= ns) return;
    uint32_t k = pack4(((const int4*)sidx)[i]);
    atomicOr(&combo[k >> 6].word, 1ull << (k & 63u));
}

// ---------------- phase 2: per-group bit counts (wave-coalesced streaming reads) ----------------
__global__ void group_popcount(const Combo* __restrict__ combo, uint32_t* __restrict__ groupSum) {
    __shared__ uint32_t s[256];
    uint32_t t = 0;
    size_t base = (size_t)blockIdx.x * GW;
    #pragma unroll
    for (int j = 0; j < 16; ++j)
        t += (uint32_t)__popcll(combo[base + j * 256u + threadIdx.x].word);
    s[threadIdx.x] = t;
    __syncthreads();
    #pragma unroll
    for (int off = 128; off > 0; off >>= 1) {
        if (threadIdx.x < (unsigned)off) s[threadIdx.x] += s[threadIdx.x + off];
        __syncthreads();
    }
    if (threadIdx.x == 0) groupSum[blockIdx.x] = s[0];
}

// single block: exclusive scan of NGROUPS group sums
__global__ void scan_groups(uint32_t* __restrict__ groupSum, int n) {
    __shared__ uint32_t s[256];
    uint32_t run = 0;
    for (int c = 0; c < n; c += 256) {
        int i = c + (int)threadIdx.x;
        uint32_t v = (i < n) ? groupSum[i] : 0u;
        s[threadIdx.x] = v;
        __syncthreads();
        #pragma unroll
        for (int off = 1; off < 256; off <<= 1) {
            uint32_t u = (threadIdx.x >= (unsigned)off) ? s[threadIdx.x - off] : 0u;
            __syncthreads();
            s[threadIdx.x] += u;
            __syncthreads();
        }
        if (i < n) groupSum[i] = s[threadIdx.x] - v + run;
        run += s[255];
        __syncthreads();
    }
}

// ---------------- phase 3: per-word prefix + sorted decoded indice ----------------
// Thread owns 16 CONTIGUOUS words (rank order == thread order). Stores the FULL
// 16B Combo record (word re-stored with its prefix) so lines become fully dirty —
// avoids partial-line RMW writebacks (round-8 lesson).
__global__ void word_prefix_indice(Combo* __restrict__ combo,
                                   const uint32_t* __restrict__ groupBase,
                                   float* __restrict__ outI) {
    __shared__ uint32_t s[256];
    const int tid = threadIdx.x;
    size_t w0 = (size_t)blockIdx.x * GW + (size_t)tid * 16;
    u64 w[16];
    uint32_t tsum = 0;
    #pragma unroll
    for (int j = 0; j < 16; ++j) { w[j] = combo[w0 + j].word; tsum += (uint32_t)__popcll(w[j]); }
    s[tid] = tsum;
    __syncthreads();
    #pragma unroll
    for (int off = 1; off < 256; off <<= 1) {
        uint32_t u = (tid >= off) ? s[tid - off] : 0u;
        __syncthreads();
        s[tid] += u;
        __syncthreads();
    }
    uint32_t run = groupBase[blockIdx.x] + s[tid] - tsum;   // exclusive rank at first word
    #pragma unroll
    for (int j = 0; j < 16; ++j) {
        u64x2 rec; rec.x = w[j]; rec.y = (u64)run;          // low 32 of .y = prefix
        ((u64x2*)combo)[w0 + j] = rec;
        u64 word = w[j];
        uint32_t kw = (uint32_t)(w0 + j) << 6;
        while (word) {
            int b = (int)__builtin_ctzll(word);
            word &= word - 1;
            uint32_t k = kw | (uint32_t)b;
            uint32_t bz = k >> 20;
            ((float4*)outI)[run++] = make_float4(
                (float)(bz / 41u), (float)(bz % 41u),
                (float)((k >> 10) & 1023u), (float)(k & 1023u));
        }
    }
}

// ---------------- phase 4: teacher probe — ONE 16B random load per row ----------------
__global__ void teacher_probe(const int* __restrict__ tidx, const Combo* __restrict__ combo,
                              uint32_t* __restrict__ cnt, int* __restrict__ pos, int nt) {
    int t = blockIdx.x * blockDim.x + threadIdx.x;
    if (t >= nt) return;
    uint32_t k = pack4(((const int4*)tidx)[t]);
    u64x2 e = ((const u64x2*)combo)[k >> 6];
    u64 word = e.x;
    u64 bit  = 1ull << (k & 63u);
    if (word & bit) {
        int p = (int)((uint32_t)e.y + (uint32_t)__popcll(word & (bit - 1ull)));
        pos[t] = p;
        atomicAdd(&cnt[p], 1u);   // ~2M atomics over ~25K lines: negligible serialization
    } else {
        pos[t] = -1;
    }
}

// zero only multi-contributor rows; cnt==1 rows are fully overwritten by plain stores
__global__ void zero_multi(const uint32_t* __restrict__ cnt, float* __restrict__ feat, int ns) {
    int s = blockIdx.x * blockDim.x + threadIdx.x;
    if (s >= ns) return;
    if (cnt[s] > 1u) {
        float4* d4 = (float4*)(feat + (size_t)s * 32);
        #pragma unroll
        for (int q = 0; q < 8; ++q) d4[q] = make_float4(0.f, 0.f, 0.f, 0.f);
    }
}

// ---------------- phase 5: feature write (no search; pos precomputed) ----------------
__global__ void teacher_write(const float* __restrict__ tfeat, const int* __restrict__ pos,
                              const uint32_t* __restrict__ cnt, float* __restrict__ feat, int nt) {
    int t = blockIdx.x * blockDim.x + threadIdx.x;
    if (t >= nt) return;
    int p = pos[t];
    if (p < 0) return;
    const float4* src = (const float4*)(tfeat + (size_t)t * 32);
    float* dst = feat + (size_t)p * 32;
    if (cnt[p] == 1u) {
        float4* d4 = (float4*)dst;
        #pragma unroll
        for (int q = 0; q < 8; ++q) d4[q] = src[q];
    } else {
        #pragma unroll
        for (int q = 0; q < 8; ++q) {
            float4 f = src[q];
            atomicAdd(dst + q * 4 + 0, f.x);
            atomicAdd(dst + q * 4 + 1, f.y);
            atomicAdd(dst + q * 4 + 2, f.z);
            atomicAdd(dst + q * 4 + 3, f.w);
        }
    }
}

extern "C" void kernel_launch(void* const* d_in, const int* in_sizes, int n_in,
                              void* d_out, int out_size, void* d_ws, size_t ws_size,
                              hipStream_t stream) {
    const float* tfeat = (const float*)d_in[0];
    const int*   tidx  = (const int*)d_in[1];
    const int*   sidx  = (const int*)d_in[2];

    const int NT = in_sizes[1] / 4;
    const int NS = in_sizes[2] / 4;

    float* feat = (float*)d_out;                        // [NS, 32]
    float* outI = (float*)d_out + (size_t)NS * 32;      // [NS, 4] as floats

    // workspace: [combo 41MiB][cnt NS*4] <- one contiguous zero-fill
    //            [groupSum 656*4][pos NT*4]            (~54MB << ~1GB ws)
    char* base = (char*)d_ws;
    Combo*    combo    = (Combo*)base;
    uint32_t* cnt      = (uint32_t*)(base + (size_t)NWORDS * sizeof(Combo));
    size_t    zeroBytes = (size_t)NWORDS * sizeof(Combo) + (size_t)NS * 4;
    uint32_t* groupSum = cnt + NS;
    int*      pos      = (int*)(groupSum + NGROUPS);

    hipMemsetAsync(d_ws, 0, zeroBytes, stream);

    set_bits<<<(NS + 255) / 256, 256, 0, stream>>>(sidx, combo, NS);
    group_popcount<<<NGROUPS, 256, 0, stream>>>(combo, groupSum);
    scan_groups<<<1, 256, 0, stream>>>(groupSum, NGROUPS);
    word_prefix_indice<<<NGROUPS, 256, 0, stream>>>(combo, groupSum, outI);
    teacher_probe<<<(NT + 255) / 256, 256, 0, stream>>>(tidx, combo, cnt, pos, NT);
    zero_multi<<<(NS + 255) / 256, 256, 0, stream>>>(cnt, feat, NS);
    teacher_write<<<(NT + 255) / 256, 256, 0, stream>>>(tfeat, pos, cnt, feat, NT);
}